// Round 10
// baseline (176.494 us; speedup 1.0000x reference)
//
#include <hip/hip_runtime.h>
#include <math.h>

#define BATCH 4
#define CH    256
#define NPIX  4096
#define DQK   32

typedef short          s16;
typedef unsigned int   uint_t;
typedef __attribute__((ext_vector_type(8))) short short8;   // 8 bf16 (4 VGPRs)
typedef __attribute__((ext_vector_type(4))) float floatx4;  // MFMA C/D 16x16
typedef __attribute__((ext_vector_type(16))) float floatx16; // MFMA C/D 32x32

__device__ __forceinline__ s16 f2bf(float f) {
  union { float f; uint_t u; } v; v.f = f;
  return (s16)((v.u + 0x8000u) >> 16);
}
__device__ __forceinline__ uint_t pk2(float a, float b) {
  union { float f; uint_t u; } x, y; x.f = a; y.f = b;
  return (((y.u + 0x8000u) >> 16) << 16) | ((x.u + 0x8000u) >> 16);
}
// single-instruction 2^x (v_exp_f32) — NOT libm exp2f (r8 lesson)
__device__ __forceinline__ float fexp2(float x) {
#if defined(__has_builtin)
#if __has_builtin(__builtin_amdgcn_exp2f)
  return __builtin_amdgcn_exp2f(x);
#else
  float r; asm("v_exp_f32 %0, %1" : "=v"(r) : "v"(x)); return r;
#endif
#else
  float r; asm("v_exp_f32 %0, %1" : "=v"(r) : "v"(x)); return r;
#endif
}

// ============ prepack: W (fp32, rows Q32|K32|V256) -> bf16 [320][256] ======
// Q rows (and bq) pre-scaled by log2(e): attn softmax = bare v_exp (2^s).
__global__ __launch_bounds__(256) void prepack(
    const float* __restrict__ Wq, const float* __restrict__ bq,
    const float* __restrict__ Wk, const float* __restrict__ bk,
    const float* __restrict__ Wv, const float* __restrict__ bv,
    s16* __restrict__ Wbf, float* __restrict__ Bsw)
{
  const float LOG2E = 1.4426950408889634f;
  const int gid = blockIdx.x * 256 + threadIdx.x;   // grid 80
  const int e0  = gid * 4;
  const int row = e0 >> 8, col = e0 & 255;
  const float* src = (row < 32) ? Wq + (size_t)row * 256
                   : (row < 64) ? Wk + (size_t)(row - 32) * 256
                                : Wv + (size_t)(row - 64) * 256;
  float4 f = *(const float4*)(src + col);
  const float sc = (row < 32) ? LOG2E : 1.f;
  uint2 o; o.x = pk2(f.x * sc, f.y * sc); o.y = pk2(f.z * sc, f.w * sc);
  *(uint2*)(Wbf + e0) = o;
  if (gid < 320)
    Bsw[gid] = (gid < 32) ? bq[gid] * LOG2E
             : (gid < 64) ? bk[gid - 32] : bv[gid - 64];
}

// ============ proj: [Q;K;V] = W'·X, 32-px tiles, grid 512 (2 blocks/CU) ====
// Out: Q,K bf16 [b][n][32] ; V in MFMA-fragment-tiled layout:
//   Vt[((b*8+c)*256+s)*512 + lane*8 + j] = V[c*32+(lane&31)][s*16+8*(lane>>5)+j]
__global__ __launch_bounds__(256, 2) void proj_mfma(
    const float* __restrict__ x, const s16* __restrict__ Wbf,
    const float* __restrict__ Bsw,
    s16* __restrict__ Qw, s16* __restrict__ Kw, s16* __restrict__ Vw)
{
  const int b  = blockIdx.x >> 7;
  const int n0 = (blockIdx.x & 127) << 5;
  const int t  = threadIdx.x;

  __shared__ s16 Xs[32][264];   // [n][k] bf16
  __shared__ s16 Os[256][40];   // V-epilogue staging [c][px], pad 40 (16B rows)

  // ---- stage X tile transposed (fp32 -> bf16) ----
  const float* xb = x + (size_t)b * CH * NPIX + n0;
  #pragma unroll
  for (int i = 0; i < 2; ++i) {
    int task = i * 256 + t;
    int ncg  = task & 7;
    int kcg  = task >> 3;
    const float* src = xb + (size_t)(kcg * 4) * NPIX + ncg * 4;
    float rows[4][4];
    *(float4*)&rows[0][0] = *(const float4*)(src);
    *(float4*)&rows[1][0] = *(const float4*)(src + NPIX);
    *(float4*)&rows[2][0] = *(const float4*)(src + 2 * NPIX);
    *(float4*)&rows[3][0] = *(const float4*)(src + 3 * NPIX);
    #pragma unroll
    for (int c = 0; c < 4; ++c) {
      uint2 pk;
      pk.x = pk2(rows[0][c], rows[1][c]);
      pk.y = pk2(rows[2][c], rows[3][c]);
      *(uint2*)&Xs[ncg * 4 + c][kcg * 4] = pk;
    }
  }
  __syncthreads();

  const int w    = t >> 6;
  const int l15  = t & 15;
  const int quad = (t & 63) >> 4;

  floatx4 acc[5][2];
  #pragma unroll
  for (int si = 0; si < 5; ++si)
    #pragma unroll
    for (int nt = 0; nt < 2; ++nt) acc[si][nt] = (floatx4){0.f, 0.f, 0.f, 0.f};

  // W fragments: register double-buffer to hide L2 latency
  short8 afc[5], afn[5];
  #pragma unroll
  for (int si = 0; si < 5; ++si) {
    const int s = w + si * 4;
    afc[si] = *(const short8*)(Wbf + (size_t)(s * 16 + l15) * 256 + quad * 8);
  }
  for (int kc = 0; kc < 8; ++kc) {
    const int k0  = kc * 32;
    const int kn0 = (kc < 7) ? k0 + 32 : 0;
    #pragma unroll
    for (int si = 0; si < 5; ++si) {
      const int s = w + si * 4;
      afn[si] = *(const short8*)(Wbf + (size_t)(s * 16 + l15) * 256 + kn0 + quad * 8);
    }
    short8 bf[2];
    #pragma unroll
    for (int nt = 0; nt < 2; ++nt)
      bf[nt] = *(const short8*)&Xs[l15 + 16 * nt][k0 + quad * 8];
    #pragma unroll
    for (int si = 0; si < 5; ++si)
      #pragma unroll
      for (int nt = 0; nt < 2; ++nt)
        acc[si][nt] = __builtin_amdgcn_mfma_f32_16x16x32_bf16(afc[si], bf[nt], acc[si][nt], 0, 0, 0);
    #pragma unroll
    for (int si = 0; si < 5; ++si) afc[si] = afn[si];
  }

  // ---- epilogue: Q/K direct; V staged in LDS then tiled-coalesced stores ----
  #pragma unroll
  for (int si = 0; si < 5; ++si) {
    const int s = w + si * 4;
    float4 bb = *(const float4*)(Bsw + 16 * s + quad * 4);
    #pragma unroll
    for (int nt = 0; nt < 2; ++nt) {
      const int px  = 16 * nt + l15;
      float v0 = acc[si][nt][0] + bb.x;
      float v1 = acc[si][nt][1] + bb.y;
      float v2 = acc[si][nt][2] + bb.z;
      float v3 = acc[si][nt][3] + bb.w;
      if (s < 4) {
        s16* dst = (s < 2) ? Qw : Kw;
        int d0 = (s & 1) * 16 + quad * 4;
        uint2 pq; pq.x = pk2(v0, v1); pq.y = pk2(v2, v3);
        *(uint2*)(dst + ((size_t)b * NPIX + n0 + px) * DQK + d0) = pq;
      } else {
        const int c0 = (s - 4) * 16 + quad * 4;
        Os[c0 + 0][px] = f2bf(v0);
        Os[c0 + 1][px] = f2bf(v1);
        Os[c0 + 2][px] = f2bf(v2);
        Os[c0 + 3][px] = f2bf(v3);
      }
    }
  }
  __syncthreads();
  // 1024 tasks = 16 frags (c 0..7 x sl 0..1) x 64 lanes, 16B coalesced stores
  #pragma unroll
  for (int rep = 0; rep < 4; ++rep) {
    const int task = rep * 256 + t;
    const int fid  = task >> 6;
    const int ln   = task & 63;
    const int c    = fid >> 1;
    const int sl   = fid & 1;
    const int row  = c * 32 + (ln & 31);
    const int col  = sl * 16 + (ln >> 5) * 8;
    *(uint4*)(Vw + (((size_t)b * 8 + c) * 256 + (n0 >> 4) + sl) * 512 + ln * 8) =
        *(const uint4*)&Os[row][col];
  }
}

// ============ attn: 256 blocks (1/CU), 16 waves, KVBLK=256 windows =========
// Same roles/math as r9 but each barrier window covers 256 keys:
//   S role:  wave w owns 16-key strip 16w of the 256, ALL 64 q
//            (4 MFMA 16x16x32 + 16 exp + swizzled Pt writes).
//   PV role: wave w -> ch-block cpv=w&7 (32 ch), key-HALF kh=w>>3 (128 k),
//            all 64 q: 16 pb b128 (4 interleaved chunks) + 16 MFMA 32x32x16.
// Barrier count 32 -> 16 (halves sync-skew/drain overhead).
// Pt[2][64][256] = 64KB; Ored (used only post-loop) ALIASES Pt -> LDS 68KB.
__global__ __launch_bounds__(1024, 4) void attn_mfma(
    const s16* __restrict__ Qw, const s16* __restrict__ Kw,
    const s16* __restrict__ Vt, const float* __restrict__ x,
    float* __restrict__ out)
{
  const int bi = blockIdx.x;          // 256 blocks
  const int b  = bi & 3;              // XCD x -> batch x&3 (K/V/Q L2-resident)
  const int qt = bi >> 2;             // 0..63
  const int n0 = qt * 64;
  const int t  = threadIdx.x;
  const int w    = t >> 6;            // wave 0..15
  const int lane = t & 63;
  const int l15  = t & 15;
  const int quad = lane >> 4;
  const int l31  = t & 31;
  const int lh   = lane >> 5;
  const int l7   = t & 7;             // == row&7 for Pt write and read rows
  const int cpv  = w & 7;             // PV: ch-block
  const int kh   = w >> 3;            // PV: 128-key half of the window

  __shared__ __align__(16) unsigned char smem[69632];
  s16   (*Pt)[64][256]   = reinterpret_cast<s16 (*)[64][256]>(smem);     // 64KB
  float (*Ored)[32][64]  = reinterpret_cast<float (*)[32][64]>(smem);    // alias
  float (*Lsum)[16]      = reinterpret_cast<float (*)[16]>(smem + 65536); // 4KB

  // Q B-frags persistent: B[d=8*quad+j][q=16tq+l15], all 64 q
  const s16* qbase = Qw + ((size_t)b * NPIX + n0) * DQK;
  short8 qb[4];
  #pragma unroll
  for (int tq = 0; tq < 4; ++tq)
    qb[tq] = *(const short8*)(qbase + (size_t)(16 * tq + l15) * DQK + quad * 8);

  floatx16 o[2];                      // o[0]: q 0..31, o[1]: q 32..63
  #pragma unroll
  for (int i = 0; i < 16; ++i) { o[0][i] = 0.f; o[1][i] = 0.f; }
  float l_part[4] = {0.f, 0.f, 0.f, 0.f};

  const s16* kbase = Kw + (size_t)b * NPIX * DQK;
  const s16* vtb   = Vt + ((size_t)(b * 8 + cpv) * 256) * 512 + lane * 8;

  // prefetch window 0: K strip + V A-frags (coalesced 1KB tiled loads)
  short8 ka_c, ka_n, va[8];
  ka_c = *(const short8*)(kbase + (size_t)(16 * w + l15) * DQK + quad * 8);
  #pragma unroll
  for (int ks = 0; ks < 8; ++ks)
    va[ks] = *(const short8*)(vtb + (size_t)(ks + 8 * kh) * 512);

  const int wslot = (((2 * w + (quad >> 1)) ^ l7) << 3) + (quad & 1) * 4;

  // ---- prologue: S for window 0 -> Pt[0] ----
  {
    floatx4 sacc[4];
    #pragma unroll
    for (int tq = 0; tq < 4; ++tq)
      sacc[tq] = __builtin_amdgcn_mfma_f32_16x16x32_bf16(
                   ka_c, qb[tq], (floatx4){0.f, 0.f, 0.f, 0.f}, 0, 0, 0);
    ka_n = *(const short8*)(kbase + (size_t)(256 + 16 * w + l15) * DQK + quad * 8);
    #pragma unroll
    for (int tq = 0; tq < 4; ++tq) {
      float p0 = fexp2(fminf(sacc[tq][0], 86.f));
      float p1 = fexp2(fminf(sacc[tq][1], 86.f));
      float p2 = fexp2(fminf(sacc[tq][2], 86.f));
      float p3 = fexp2(fminf(sacc[tq][3], 86.f));
      l_part[tq] += (p0 + p1) + (p2 + p3);
      uint2 pk; pk.x = pk2(p0, p1); pk.y = pk2(p2, p3);
      *(uint2*)&Pt[0][16 * tq + l15][wslot] = pk;
    }
    ka_c = ka_n;
  }
  __syncthreads();

  // pb read / MFMA macros — all indices compile-time constant
#define PB_RD(P, KSL, KG) {                                                  \
    const int rs = ((2 * (8 * kh + (KG)) + lh) ^ l7) << 3;                   \
    pc##P[KSL][0] = *(const short8*)&Pt[buf][l31     ][rs];                  \
    pc##P[KSL][1] = *(const short8*)&Pt[buf][32 + l31][rs]; }
#define PB_MM(P, KSL, KG) {                                                  \
    o[0] = __builtin_amdgcn_mfma_f32_32x32x16_bf16(va[KG], pc##P[KSL][0], o[0], 0, 0, 0); \
    o[1] = __builtin_amdgcn_mfma_f32_32x32x16_bf16(va[KG], pc##P[KSL][1], o[1], 0, 0, 0); }

  for (int kt2 = 0; kt2 < 16; ++kt2) {
    const int buf = kt2 & 1;
    short8 pc0[2][2], pc1[2][2];

    // ---- 1) issue first pb chunk (latency hides under S below) ----
    PB_RD(0, 0, 0); PB_RD(0, 1, 1);

    // ---- 2) S for window kt2+1 -> Pt[buf^1] (disjoint buffer) ----
    if (kt2 < 15) {
      floatx4 sacc[4];
      #pragma unroll
      for (int tq = 0; tq < 4; ++tq)
        sacc[tq] = __builtin_amdgcn_mfma_f32_16x16x32_bf16(
                     ka_c, qb[tq], (floatx4){0.f, 0.f, 0.f, 0.f}, 0, 0, 0);
      const int mn2 = (kt2 < 14) ? (kt2 + 2) * 256 : 0;
      ka_n = *(const short8*)(kbase + (size_t)(mn2 + 16 * w + l15) * DQK + quad * 8);
      #pragma unroll
      for (int tq = 0; tq < 4; ++tq) {
        float p0 = fexp2(fminf(sacc[tq][0], 86.f));
        float p1 = fexp2(fminf(sacc[tq][1], 86.f));
        float p2 = fexp2(fminf(sacc[tq][2], 86.f));
        float p3 = fexp2(fminf(sacc[tq][3], 86.f));
        l_part[tq] += (p0 + p1) + (p2 + p3);
        uint2 pk; pk.x = pk2(p0, p1); pk.y = pk2(p2, p3);
        *(uint2*)&Pt[buf ^ 1][16 * tq + l15][wslot] = pk;
      }
      ka_c = ka_n;
    }

    // ---- 3) PV: 4 chunks, read chunk j+1 while MFMA'ing chunk j ----
    __builtin_amdgcn_s_setprio(1);
    PB_RD(1, 0, 2); PB_RD(1, 1, 3);
    PB_MM(0, 0, 0); PB_MM(0, 1, 1);
    PB_RD(0, 0, 4); PB_RD(0, 1, 5);
    PB_MM(1, 0, 2); PB_MM(1, 1, 3);
    PB_RD(1, 0, 6); PB_RD(1, 1, 7);
    PB_MM(0, 0, 4); PB_MM(0, 1, 5);
    PB_MM(1, 0, 6); PB_MM(1, 1, 7);
    __builtin_amdgcn_s_setprio(0);

    // ---- 4) V refill for window kt2+1 (wraps harmlessly at kt2=15) ----
    const int sn = ((kt2 + 1) & 15) * 16;
    #pragma unroll
    for (int ks = 0; ks < 8; ++ks)
      va[ks] = *(const short8*)(vtb + (size_t)(sn + 8 * kh + ks) * 512);

    __syncthreads();   // publish Pt[buf^1]; all reads of Pt[buf] done
  }
#undef PB_RD
#undef PB_MM

  // ---- final l reduction: quads (shfl) then strips (LDS, once) ----
  #pragma unroll
  for (int tq = 0; tq < 4; ++tq) {
    l_part[tq] += __shfl_xor(l_part[tq], 16);
    l_part[tq] += __shfl_xor(l_part[tq], 32);
  }
  if (quad == 0) {
    #pragma unroll
    for (int tq = 0; tq < 4; ++tq) Lsum[16 * tq + l15][w] = l_part[tq];
  }
  // kh=1 waves stage their partial O for reduction (Ored aliases Pt —
  // safe: all Pt reads completed before the loop's final barrier)
  if (kh == 1) {
    #pragma unroll
    for (int r = 0; r < 16; ++r) {
      const int chrow = (r & 3) + 8 * (r >> 2) + 4 * lh;
      Ored[cpv][chrow][l31]      = o[0][r];
      Ored[cpv][chrow][32 + l31] = o[1][r];
    }
  }
  __syncthreads();

  // ---- epilogue (kh=0 waves): sum key-halves, normalize, residual ----
  if (kh == 0) {
    const int q0 = l31, q1 = 32 + l31;
    float4 a0 = *(const float4*)&Lsum[q0][0];
    float4 a1 = *(const float4*)&Lsum[q0][4];
    float4 a2 = *(const float4*)&Lsum[q0][8];
    float4 a3 = *(const float4*)&Lsum[q0][12];
    float4 b0 = *(const float4*)&Lsum[q1][0];
    float4 b1 = *(const float4*)&Lsum[q1][4];
    float4 b2 = *(const float4*)&Lsum[q1][8];
    float4 b3 = *(const float4*)&Lsum[q1][12];
    float inv0 = 1.f / ((((a0.x + a0.y) + (a0.z + a0.w)) +
                         ((a1.x + a1.y) + (a1.z + a1.w))) +
                        (((a2.x + a2.y) + (a2.z + a2.w)) +
                         ((a3.x + a3.y) + (a3.z + a3.w))));
    float inv1 = 1.f / ((((b0.x + b0.y) + (b0.z + b0.w)) +
                         ((b1.x + b1.y) + (b1.z + b1.w))) +
                        (((b2.x + b2.y) + (b2.z + b2.w)) +
                         ((b3.x + b3.y) + (b3.z + b3.w))));
    #pragma unroll
    for (int r = 0; r < 16; ++r) {
      const int chrow = (r & 3) + 8 * (r >> 2) + 4 * lh;
      const int ch = cpv * 32 + chrow;
      const float s0 = o[0][r] + Ored[cpv][chrow][l31];
      const float s1 = o[1][r] + Ored[cpv][chrow][32 + l31];
      const size_t off0 = ((size_t)b * CH + ch) * NPIX + n0 + q0;
      const size_t off1 = ((size_t)b * CH + ch) * NPIX + n0 + q1;
      out[off0] = fmaf(s0, inv0, x[off0]);
      out[off1] = fmaf(s1, inv1, x[off1]);
    }
  }
}

extern "C" void kernel_launch(void* const* d_in, const int* in_sizes, int n_in,
                              void* d_out, int out_size, void* d_ws, size_t ws_size,
                              hipStream_t stream) {
  (void)in_sizes; (void)n_in; (void)out_size; (void)ws_size;
  const float* x  = (const float*)d_in[0];
  const float* Wq = (const float*)d_in[1];
  const float* bq = (const float*)d_in[2];
  const float* Wk = (const float*)d_in[3];
  const float* bk = (const float*)d_in[4];
  const float* Wv = (const float*)d_in[5];
  const float* bv = (const float*)d_in[6];
  float* out = (float*)d_out;

  // ws: Qw 1 MiB @0 | Kw @1 MiB | Vt @2 MiB (8 MiB, tiled) | Wbf @10 MiB |
  //     Bsw @10.25 MiB
  unsigned char* ws = (unsigned char*)d_ws;
  s16*   Qw  = (s16*)ws;
  s16*   Kw  = (s16*)(ws + (size_t)1 * 1024 * 1024);
  s16*   Vt  = (s16*)(ws + (size_t)2 * 1024 * 1024);
  s16*   Wbf = (s16*)(ws + (size_t)10 * 1024 * 1024);
  float* Bsw = (float*)(ws + (size_t)10 * 1024 * 1024 + 256 * 1024);

  hipLaunchKernelGGL(prepack, dim3(80), dim3(256), 0, stream,
                     Wq, bq, Wk, bk, Wv, bv, Wbf, Bsw);
  hipLaunchKernelGGL(proj_mfma, dim3(512), dim3(256), 0, stream,
                     x, Wbf, Bsw, Qw, Kw, Vt);
  hipLaunchKernelGGL(attn_mfma, dim3(256), dim3(1024), 0, stream,
                     Qw, Kw, Vt, x, out);
}

// Round 11
// 142.939 us; speedup vs baseline: 1.2347x; 1.2347x over previous
//
#include <hip/hip_runtime.h>
#include <math.h>

#define BATCH 4
#define CH    256
#define NPIX  4096
#define DQK   32

typedef short          s16;
typedef unsigned int   uint_t;
typedef __attribute__((ext_vector_type(8))) short short8;   // 8 bf16 (4 VGPRs)
typedef __attribute__((ext_vector_type(4))) float floatx4;  // MFMA C/D 16x16
typedef __attribute__((ext_vector_type(16))) float floatx16; // MFMA C/D 32x32

__device__ __forceinline__ s16 f2bf(float f) {
  union { float f; uint_t u; } v; v.f = f;
  return (s16)((v.u + 0x8000u) >> 16);
}
__device__ __forceinline__ uint_t pk2(float a, float b) {
  union { float f; uint_t u; } x, y; x.f = a; y.f = b;
  return (((y.u + 0x8000u) >> 16) << 16) | ((x.u + 0x8000u) >> 16);
}
// single-instruction 2^x (v_exp_f32) — NOT libm exp2f (r8 lesson)
__device__ __forceinline__ float fexp2(float x) {
#if defined(__has_builtin)
#if __has_builtin(__builtin_amdgcn_exp2f)
  return __builtin_amdgcn_exp2f(x);
#else
  float r; asm("v_exp_f32 %0, %1" : "=v"(r) : "v"(x)); return r;
#endif
#else
  float r; asm("v_exp_f32 %0, %1" : "=v"(r) : "v"(x)); return r;
#endif
}

// ============ prepack: W (fp32, rows Q32|K32|V256) -> bf16 [320][256] ======
// Q rows (and bq) pre-scaled by log2(e): attn softmax = bare v_exp (2^s).
__global__ __launch_bounds__(256) void prepack(
    const float* __restrict__ Wq, const float* __restrict__ bq,
    const float* __restrict__ Wk, const float* __restrict__ bk,
    const float* __restrict__ Wv, const float* __restrict__ bv,
    s16* __restrict__ Wbf, float* __restrict__ Bsw)
{
  const float LOG2E = 1.4426950408889634f;
  const int gid = blockIdx.x * 256 + threadIdx.x;   // grid 80
  const int e0  = gid * 4;
  const int row = e0 >> 8, col = e0 & 255;
  const float* src = (row < 32) ? Wq + (size_t)row * 256
                   : (row < 64) ? Wk + (size_t)(row - 32) * 256
                                : Wv + (size_t)(row - 64) * 256;
  float4 f = *(const float4*)(src + col);
  const float sc = (row < 32) ? LOG2E : 1.f;
  uint2 o; o.x = pk2(f.x * sc, f.y * sc); o.y = pk2(f.z * sc, f.w * sc);
  *(uint2*)(Wbf + e0) = o;
  if (gid < 320)
    Bsw[gid] = (gid < 32) ? bq[gid] * LOG2E
             : (gid < 64) ? bk[gid - 32] : bv[gid - 64];
}

// ============ proj: [Q;K;V] = W'·X, 32-px tiles, grid 512 (2 blocks/CU) ====
// Out: Q,K bf16 [b][n][32] ; V in MFMA-fragment-tiled layout:
//   Vt[((b*8+c)*256+s)*512 + lane*8 + j] = V[c*32+(lane&31)][s*16+8*(lane>>5)+j]
__global__ __launch_bounds__(256, 2) void proj_mfma(
    const float* __restrict__ x, const s16* __restrict__ Wbf,
    const float* __restrict__ Bsw,
    s16* __restrict__ Qw, s16* __restrict__ Kw, s16* __restrict__ Vw)
{
  const int b  = blockIdx.x >> 7;
  const int n0 = (blockIdx.x & 127) << 5;
  const int t  = threadIdx.x;

  __shared__ s16 Xs[32][264];   // [n][k] bf16
  __shared__ s16 Os[256][40];   // V-epilogue staging [c][px], pad 40 (16B rows)

  // ---- stage X tile transposed (fp32 -> bf16) ----
  const float* xb = x + (size_t)b * CH * NPIX + n0;
  #pragma unroll
  for (int i = 0; i < 2; ++i) {
    int task = i * 256 + t;
    int ncg  = task & 7;
    int kcg  = task >> 3;
    const float* src = xb + (size_t)(kcg * 4) * NPIX + ncg * 4;
    float rows[4][4];
    *(float4*)&rows[0][0] = *(const float4*)(src);
    *(float4*)&rows[1][0] = *(const float4*)(src + NPIX);
    *(float4*)&rows[2][0] = *(const float4*)(src + 2 * NPIX);
    *(float4*)&rows[3][0] = *(const float4*)(src + 3 * NPIX);
    #pragma unroll
    for (int c = 0; c < 4; ++c) {
      uint2 pk;
      pk.x = pk2(rows[0][c], rows[1][c]);
      pk.y = pk2(rows[2][c], rows[3][c]);
      *(uint2*)&Xs[ncg * 4 + c][kcg * 4] = pk;
    }
  }
  __syncthreads();

  const int w    = t >> 6;
  const int l15  = t & 15;
  const int quad = (t & 63) >> 4;

  floatx4 acc[5][2];
  #pragma unroll
  for (int si = 0; si < 5; ++si)
    #pragma unroll
    for (int nt = 0; nt < 2; ++nt) acc[si][nt] = (floatx4){0.f, 0.f, 0.f, 0.f};

  // W fragments: register double-buffer to hide L2 latency
  short8 afc[5], afn[5];
  #pragma unroll
  for (int si = 0; si < 5; ++si) {
    const int s = w + si * 4;
    afc[si] = *(const short8*)(Wbf + (size_t)(s * 16 + l15) * 256 + quad * 8);
  }
  for (int kc = 0; kc < 8; ++kc) {
    const int k0  = kc * 32;
    const int kn0 = (kc < 7) ? k0 + 32 : 0;
    #pragma unroll
    for (int si = 0; si < 5; ++si) {
      const int s = w + si * 4;
      afn[si] = *(const short8*)(Wbf + (size_t)(s * 16 + l15) * 256 + kn0 + quad * 8);
    }
    short8 bf[2];
    #pragma unroll
    for (int nt = 0; nt < 2; ++nt)
      bf[nt] = *(const short8*)&Xs[l15 + 16 * nt][k0 + quad * 8];
    #pragma unroll
    for (int si = 0; si < 5; ++si)
      #pragma unroll
      for (int nt = 0; nt < 2; ++nt)
        acc[si][nt] = __builtin_amdgcn_mfma_f32_16x16x32_bf16(afc[si], bf[nt], acc[si][nt], 0, 0, 0);
    #pragma unroll
    for (int si = 0; si < 5; ++si) afc[si] = afn[si];
  }

  // ---- epilogue: Q/K direct; V staged in LDS then tiled-coalesced stores ----
  #pragma unroll
  for (int si = 0; si < 5; ++si) {
    const int s = w + si * 4;
    float4 bb = *(const float4*)(Bsw + 16 * s + quad * 4);
    #pragma unroll
    for (int nt = 0; nt < 2; ++nt) {
      const int px  = 16 * nt + l15;
      float v0 = acc[si][nt][0] + bb.x;
      float v1 = acc[si][nt][1] + bb.y;
      float v2 = acc[si][nt][2] + bb.z;
      float v3 = acc[si][nt][3] + bb.w;
      if (s < 4) {
        s16* dst = (s < 2) ? Qw : Kw;
        int d0 = (s & 1) * 16 + quad * 4;
        uint2 pq; pq.x = pk2(v0, v1); pq.y = pk2(v2, v3);
        *(uint2*)(dst + ((size_t)b * NPIX + n0 + px) * DQK + d0) = pq;
      } else {
        const int c0 = (s - 4) * 16 + quad * 4;
        Os[c0 + 0][px] = f2bf(v0);
        Os[c0 + 1][px] = f2bf(v1);
        Os[c0 + 2][px] = f2bf(v2);
        Os[c0 + 3][px] = f2bf(v3);
      }
    }
  }
  __syncthreads();
  // 1024 tasks = 16 frags (c 0..7 x sl 0..1) x 64 lanes, 16B coalesced stores
  #pragma unroll
  for (int rep = 0; rep < 4; ++rep) {
    const int task = rep * 256 + t;
    const int fid  = task >> 6;
    const int ln   = task & 63;
    const int c    = fid >> 1;
    const int sl   = fid & 1;
    const int row  = c * 32 + (ln & 31);
    const int col  = sl * 16 + (ln >> 5) * 8;
    *(uint4*)(Vw + (((size_t)b * 8 + c) * 256 + (n0 >> 4) + sl) * 512 + ln * 8) =
        *(const uint4*)&Os[row][col];
  }
}

// ============ attn: 512 blocks (2/CU), 8 waves, 32-q tiles (TLP) ===========
// block = (b = bi&3 [XCD-locked], qt = bi>>2 in 0..127), 32 queries, 256 ch.
// Two INDEPENDENT blocks per CU: their barrier windows interleave freely,
// hiding the per-window skew/drain that capped the 16-wave gang (r9).
// S role  (wave w): 16-key strip 16w, 32 q -> 2 MFMA 16x16x32 + 8 exp + Pt.
// PV role (wave w): 32 ch (c = w), FULL 128 k, 32 q -> 8 pb b128 + 8 MFMA
//   32x32x16 into a single floatx16 (no kh split, no Ored, VGPR ~105).
// Per-CU LDS traffic unchanged (broadcast amp = 8 ch-blocks); V/K L2 reads
// 2x (q-tiles halved) — still under the L2 BW floor at the target time.
__global__ __launch_bounds__(512, 4) void attn_mfma(
    const s16* __restrict__ Qw, const s16* __restrict__ Kw,
    const s16* __restrict__ Vt, const float* __restrict__ x,
    float* __restrict__ out)
{
  const int bi = blockIdx.x;          // 512 blocks
  const int b  = bi & 3;              // XCD x -> batch x&3 (K/V/Q L2-resident)
  const int qt = bi >> 2;             // 0..127
  const int n0 = qt * 32;
  const int t  = threadIdx.x;
  const int w    = t >> 6;            // wave 0..7
  const int lane = t & 63;
  const int l15  = t & 15;
  const int quad = lane >> 4;
  const int l31  = t & 31;
  const int lh   = lane >> 5;
  const int l7   = t & 7;             // == row&7 for Pt write and read rows

  __shared__ s16  Pt[2][32][128];     // P^T, rows q (256B), swizzled 16B slots
  __shared__ float Lsum[32][8];

  // Q B-frags persistent: B[d=8*quad+j][q = 16tq + l15], 32 q
  const s16* qbase = Qw + ((size_t)b * NPIX + n0) * DQK;
  short8 qb[2];
  #pragma unroll
  for (int tq = 0; tq < 2; ++tq)
    qb[tq] = *(const short8*)(qbase + (size_t)(16 * tq + l15) * DQK + quad * 8);

  floatx16 o;                         // O[32ch][32q] for this wave
  #pragma unroll
  for (int i = 0; i < 16; ++i) o[i] = 0.f;
  float l_part[2] = {0.f, 0.f};

  const s16* kbase = Kw + (size_t)b * NPIX * DQK;
  const s16* vtb   = Vt + ((size_t)(b * 8 + w) * 256) * 512 + lane * 8;

  // prefetch window 0: K strip + V A-frags (coalesced 1KB tiled loads)
  short8 ka_c, ka_n, va[8];
  ka_c = *(const short8*)(kbase + (size_t)(16 * w + l15) * DQK + quad * 8);
  #pragma unroll
  for (int ks = 0; ks < 8; ++ks)
    va[ks] = *(const short8*)(vtb + (size_t)ks * 512);

  const int wslot = (((2 * w + (quad >> 1)) ^ l7) << 3) + (quad & 1) * 4;

  // ---- prologue: S for window 0 -> Pt[0] ----
  {
    floatx4 sacc[2];
    #pragma unroll
    for (int tq = 0; tq < 2; ++tq)
      sacc[tq] = __builtin_amdgcn_mfma_f32_16x16x32_bf16(
                   ka_c, qb[tq], (floatx4){0.f, 0.f, 0.f, 0.f}, 0, 0, 0);
    ka_n = *(const short8*)(kbase + (size_t)(128 + 16 * w + l15) * DQK + quad * 8);
    #pragma unroll
    for (int tq = 0; tq < 2; ++tq) {
      float p0 = fexp2(fminf(sacc[tq][0], 86.f));
      float p1 = fexp2(fminf(sacc[tq][1], 86.f));
      float p2 = fexp2(fminf(sacc[tq][2], 86.f));
      float p3 = fexp2(fminf(sacc[tq][3], 86.f));
      l_part[tq] += (p0 + p1) + (p2 + p3);
      uint2 pk; pk.x = pk2(p0, p1); pk.y = pk2(p2, p3);
      *(uint2*)&Pt[0][16 * tq + l15][wslot] = pk;
    }
    ka_c = ka_n;
  }
  __syncthreads();

  for (int kt = 0; kt < 32; ++kt) {
    const int buf = kt & 1;

    // ---- 1) issue Pt reads for window kt (latency hides under S below) ----
    short8 pb[8];
    #pragma unroll
    for (int ks = 0; ks < 8; ++ks) {
      const int rslot = ((2 * ks + lh) ^ l7) << 3;
      pb[ks] = *(const short8*)&Pt[buf][l31][rslot];
    }

    // ---- 2) S for window kt+1 -> Pt[buf^1] (disjoint buffer, no race) ----
    if (kt < 31) {
      floatx4 sacc[2];
      #pragma unroll
      for (int tq = 0; tq < 2; ++tq)
        sacc[tq] = __builtin_amdgcn_mfma_f32_16x16x32_bf16(
                     ka_c, qb[tq], (floatx4){0.f, 0.f, 0.f, 0.f}, 0, 0, 0);
      const int mn2 = (kt < 30) ? (kt + 2) * 128 : 0;
      ka_n = *(const short8*)(kbase + (size_t)(mn2 + 16 * w + l15) * DQK + quad * 8);
      #pragma unroll
      for (int tq = 0; tq < 2; ++tq) {
        float p0 = fexp2(fminf(sacc[tq][0], 86.f));
        float p1 = fexp2(fminf(sacc[tq][1], 86.f));
        float p2 = fexp2(fminf(sacc[tq][2], 86.f));
        float p3 = fexp2(fminf(sacc[tq][3], 86.f));
        l_part[tq] += (p0 + p1) + (p2 + p3);
        uint2 pk; pk.x = pk2(p0, p1); pk.y = pk2(p2, p3);
        *(uint2*)&Pt[buf ^ 1][16 * tq + l15][wslot] = pk;
      }
      ka_c = ka_n;
    }

    // ---- 3) PV: O[32ch][32q] += V[32ch][128k]·P^T[128k][32q] ----
    __builtin_amdgcn_s_setprio(1);
    #pragma unroll
    for (int ks = 0; ks < 8; ++ks)
      o = __builtin_amdgcn_mfma_f32_32x32x16_bf16(va[ks], pb[ks], o, 0, 0, 0);
    __builtin_amdgcn_s_setprio(0);

    // ---- 4) V refill for window kt+1 (wraps harmlessly at kt=31) ----
    const int sn = ((kt + 1) & 31) * 8;
    #pragma unroll
    for (int ks = 0; ks < 8; ++ks)
      va[ks] = *(const short8*)(vtb + (size_t)(sn + ks) * 512);

    __syncthreads();   // publish Pt[buf^1]; all reads of Pt[buf] done
  }

  // ---- final l reduction: quads (shfl) then strips (LDS, once) ----
  #pragma unroll
  for (int tq = 0; tq < 2; ++tq) {
    l_part[tq] += __shfl_xor(l_part[tq], 16);
    l_part[tq] += __shfl_xor(l_part[tq], 32);
  }
  if (quad == 0) {
    #pragma unroll
    for (int tq = 0; tq < 2; ++tq) Lsum[16 * tq + l15][w] = l_part[tq];
  }
  __syncthreads();

  // ---- epilogue (all 8 waves): normalize + residual. 32x32 C/D:
  //      col = q = l31, row = ch = 32w + (r&3) + 8*(r>>2) + 4*lh ----
  {
    const int q = l31;
    float4 s0 = *(const float4*)&Lsum[q][0];
    float4 s1 = *(const float4*)&Lsum[q][4];
    float invq = 1.f / (((s0.x + s0.y) + (s0.z + s0.w)) +
                        ((s1.x + s1.y) + (s1.z + s1.w)));
    #pragma unroll
    for (int r = 0; r < 16; ++r) {
      const int ch = 32 * w + (r & 3) + 8 * (r >> 2) + 4 * lh;
      const size_t off = ((size_t)b * CH + ch) * NPIX + n0 + q;
      out[off] = fmaf(o[r], invq, x[off]);
    }
  }
}

extern "C" void kernel_launch(void* const* d_in, const int* in_sizes, int n_in,
                              void* d_out, int out_size, void* d_ws, size_t ws_size,
                              hipStream_t stream) {
  (void)in_sizes; (void)n_in; (void)out_size; (void)ws_size;
  const float* x  = (const float*)d_in[0];
  const float* Wq = (const float*)d_in[1];
  const float* bq = (const float*)d_in[2];
  const float* Wk = (const float*)d_in[3];
  const float* bk = (const float*)d_in[4];
  const float* Wv = (const float*)d_in[5];
  const float* bv = (const float*)d_in[6];
  float* out = (float*)d_out;

  // ws: Qw 1 MiB @0 | Kw @1 MiB | Vt @2 MiB (8 MiB, tiled) | Wbf @10 MiB |
  //     Bsw @10.25 MiB
  unsigned char* ws = (unsigned char*)d_ws;
  s16*   Qw  = (s16*)ws;
  s16*   Kw  = (s16*)(ws + (size_t)1 * 1024 * 1024);
  s16*   Vt  = (s16*)(ws + (size_t)2 * 1024 * 1024);
  s16*   Wbf = (s16*)(ws + (size_t)10 * 1024 * 1024);
  float* Bsw = (float*)(ws + (size_t)10 * 1024 * 1024 + 256 * 1024);

  hipLaunchKernelGGL(prepack, dim3(80), dim3(256), 0, stream,
                     Wq, bq, Wk, bk, Wv, bv, Wbf, Bsw);
  hipLaunchKernelGGL(proj_mfma, dim3(512), dim3(256), 0, stream,
                     x, Wbf, Bsw, Qw, Kw, Vt);
  hipLaunchKernelGGL(attn_mfma, dim3(512), dim3(512), 0, stream,
                     Qw, Kw, Vt, x, out);
}

// Round 12
// 137.058 us; speedup vs baseline: 1.2877x; 1.0429x over previous
//
#include <hip/hip_runtime.h>
#include <math.h>

#define BATCH 4
#define CH    256
#define NPIX  4096
#define DQK   32

typedef short          s16;
typedef unsigned int   uint_t;
typedef __attribute__((ext_vector_type(8))) short short8;   // 8 bf16 (4 VGPRs)
typedef __attribute__((ext_vector_type(4))) float floatx4;  // MFMA C/D 16x16
typedef __attribute__((ext_vector_type(16))) float floatx16; // MFMA C/D 32x32

__device__ __forceinline__ s16 f2bf(float f) {
  union { float f; uint_t u; } v; v.f = f;
  return (s16)((v.u + 0x8000u) >> 16);
}
__device__ __forceinline__ uint_t pk2(float a, float b) {
  union { float f; uint_t u; } x, y; x.f = a; y.f = b;
  return (((y.u + 0x8000u) >> 16) << 16) | ((x.u + 0x8000u) >> 16);
}
// single-instruction 2^x (v_exp_f32) — NOT libm exp2f (r8 lesson: libm adds
// ~10 VALU ops of edge-case handling without fast-math)
__device__ __forceinline__ float fexp2(float x) {
#if defined(__has_builtin)
#if __has_builtin(__builtin_amdgcn_exp2f)
  return __builtin_amdgcn_exp2f(x);
#else
  float r; asm("v_exp_f32 %0, %1" : "=v"(r) : "v"(x)); return r;
#endif
#else
  float r; asm("v_exp_f32 %0, %1" : "=v"(r) : "v"(x)); return r;
#endif
}

// ============ prepack: W (fp32, rows Q32|K32|V256) -> bf16 [320][256] ======
// Q rows (and bq) pre-scaled by log2(e): attn softmax = bare v_exp (2^s).
__global__ __launch_bounds__(256) void prepack(
    const float* __restrict__ Wq, const float* __restrict__ bq,
    const float* __restrict__ Wk, const float* __restrict__ bk,
    const float* __restrict__ Wv, const float* __restrict__ bv,
    s16* __restrict__ Wbf, float* __restrict__ Bsw)
{
  const float LOG2E = 1.4426950408889634f;
  const int gid = blockIdx.x * 256 + threadIdx.x;   // grid 80
  const int e0  = gid * 4;
  const int row = e0 >> 8, col = e0 & 255;
  const float* src = (row < 32) ? Wq + (size_t)row * 256
                   : (row < 64) ? Wk + (size_t)(row - 32) * 256
                                : Wv + (size_t)(row - 64) * 256;
  float4 f = *(const float4*)(src + col);
  const float sc = (row < 32) ? LOG2E : 1.f;
  uint2 o; o.x = pk2(f.x * sc, f.y * sc); o.y = pk2(f.z * sc, f.w * sc);
  *(uint2*)(Wbf + e0) = o;
  if (gid < 320)
    Bsw[gid] = (gid < 32) ? bq[gid] * LOG2E
             : (gid < 64) ? bk[gid - 32] : bv[gid - 64];
}

// ============ proj: [Q;K;V] = W'·X, 32-px tiles, grid 512 (2 blocks/CU) ====
// Out: Q,K bf16 [b][n][32] ; V in MFMA-fragment-tiled layout:
//   Vt[((b*8+c)*256+s)*512 + lane*8 + j] = V[c*32+(lane&31)][s*16+8*(lane>>5)+j]
// so attn's A-frag load for (c, k16-block s) is ONE coalesced 1KB b128/wave.
__global__ __launch_bounds__(256, 2) void proj_mfma(
    const float* __restrict__ x, const s16* __restrict__ Wbf,
    const float* __restrict__ Bsw,
    s16* __restrict__ Qw, s16* __restrict__ Kw, s16* __restrict__ Vw)
{
  const int b  = blockIdx.x >> 7;
  const int n0 = (blockIdx.x & 127) << 5;
  const int t  = threadIdx.x;

  __shared__ s16 Xs[32][264];   // [n][k] bf16
  __shared__ s16 Os[256][40];   // V-epilogue staging [c][px], pad 40 (16B rows)

  // ---- stage X tile transposed (fp32 -> bf16) ----
  const float* xb = x + (size_t)b * CH * NPIX + n0;
  #pragma unroll
  for (int i = 0; i < 2; ++i) {
    int task = i * 256 + t;
    int ncg  = task & 7;
    int kcg  = task >> 3;
    const float* src = xb + (size_t)(kcg * 4) * NPIX + ncg * 4;
    float rows[4][4];
    *(float4*)&rows[0][0] = *(const float4*)(src);
    *(float4*)&rows[1][0] = *(const float4*)(src + NPIX);
    *(float4*)&rows[2][0] = *(const float4*)(src + 2 * NPIX);
    *(float4*)&rows[3][0] = *(const float4*)(src + 3 * NPIX);
    #pragma unroll
    for (int c = 0; c < 4; ++c) {
      uint2 pk;
      pk.x = pk2(rows[0][c], rows[1][c]);
      pk.y = pk2(rows[2][c], rows[3][c]);
      *(uint2*)&Xs[ncg * 4 + c][kcg * 4] = pk;
    }
  }
  __syncthreads();

  const int w    = t >> 6;
  const int l15  = t & 15;
  const int quad = (t & 63) >> 4;

  floatx4 acc[5][2];
  #pragma unroll
  for (int si = 0; si < 5; ++si)
    #pragma unroll
    for (int nt = 0; nt < 2; ++nt) acc[si][nt] = (floatx4){0.f, 0.f, 0.f, 0.f};

  // W fragments: register double-buffer to hide L2 latency
  short8 afc[5], afn[5];
  #pragma unroll
  for (int si = 0; si < 5; ++si) {
    const int s = w + si * 4;
    afc[si] = *(const short8*)(Wbf + (size_t)(s * 16 + l15) * 256 + quad * 8);
  }
  for (int kc = 0; kc < 8; ++kc) {
    const int k0  = kc * 32;
    const int kn0 = (kc < 7) ? k0 + 32 : 0;
    #pragma unroll
    for (int si = 0; si < 5; ++si) {
      const int s = w + si * 4;
      afn[si] = *(const short8*)(Wbf + (size_t)(s * 16 + l15) * 256 + kn0 + quad * 8);
    }
    short8 bf[2];
    #pragma unroll
    for (int nt = 0; nt < 2; ++nt)
      bf[nt] = *(const short8*)&Xs[l15 + 16 * nt][k0 + quad * 8];
    #pragma unroll
    for (int si = 0; si < 5; ++si)
      #pragma unroll
      for (int nt = 0; nt < 2; ++nt)
        acc[si][nt] = __builtin_amdgcn_mfma_f32_16x16x32_bf16(afc[si], bf[nt], acc[si][nt], 0, 0, 0);
    #pragma unroll
    for (int si = 0; si < 5; ++si) afc[si] = afn[si];
  }

  // ---- epilogue: Q/K direct; V staged in LDS then tiled-coalesced stores ----
  #pragma unroll
  for (int si = 0; si < 5; ++si) {
    const int s = w + si * 4;
    float4 bb = *(const float4*)(Bsw + 16 * s + quad * 4);
    #pragma unroll
    for (int nt = 0; nt < 2; ++nt) {
      const int px  = 16 * nt + l15;
      float v0 = acc[si][nt][0] + bb.x;
      float v1 = acc[si][nt][1] + bb.y;
      float v2 = acc[si][nt][2] + bb.z;
      float v3 = acc[si][nt][3] + bb.w;
      if (s < 4) {
        s16* dst = (s < 2) ? Qw : Kw;
        int d0 = (s & 1) * 16 + quad * 4;
        uint2 pq; pq.x = pk2(v0, v1); pq.y = pk2(v2, v3);
        *(uint2*)(dst + ((size_t)b * NPIX + n0 + px) * DQK + d0) = pq;
      } else {
        const int c0 = (s - 4) * 16 + quad * 4;
        Os[c0 + 0][px] = f2bf(v0);
        Os[c0 + 1][px] = f2bf(v1);
        Os[c0 + 2][px] = f2bf(v2);
        Os[c0 + 3][px] = f2bf(v3);
      }
    }
  }
  __syncthreads();
  // 1024 tasks = 16 frags (c 0..7 x sl 0..1) x 64 lanes, 16B coalesced stores
  #pragma unroll
  for (int rep = 0; rep < 4; ++rep) {
    const int task = rep * 256 + t;
    const int fid  = task >> 6;
    const int ln   = task & 63;
    const int c    = fid >> 1;
    const int sl   = fid & 1;
    const int row  = c * 32 + (ln & 31);
    const int col  = sl * 16 + (ln >> 5) * 8;
    *(uint4*)(Vw + (((size_t)b * 8 + c) * 256 + (n0 >> 4) + sl) * 512 + ln * 8) =
        *(const uint4*)&Os[row][col];
  }
}

// ============ attn: 256 blocks (1/CU), 16 waves, K-split PV, pipelined =====
// r9 == best measured configuration (attn 49.8 us). Restored verbatim after
// six structural alternatives all measured worse (r4 80, r6 57, r8 55,
// r10 98, r11 59, r7-fused 272).
__global__ __launch_bounds__(1024, 4) void attn_mfma(
    const s16* __restrict__ Qw, const s16* __restrict__ Kw,
    const s16* __restrict__ Vt, const float* __restrict__ x,
    float* __restrict__ out)
{
  const int bi = blockIdx.x;          // 256 blocks
  const int b  = bi & 3;              // XCD x -> batch x&3 (K/V/Q L2-resident)
  const int qt = bi >> 2;             // 0..63
  const int n0 = qt * 64;
  const int t  = threadIdx.x;
  const int w    = t >> 6;            // wave 0..15
  const int lane = t & 63;
  const int l15  = t & 15;
  const int quad = lane >> 4;
  const int l31  = t & 31;
  const int lh   = lane >> 5;
  const int l7   = t & 7;             // == row&7 for Pt write and read rows
  const int sw   = w & 7;             // S: key strip  == PV: ch-block c
  const int sq   = w >> 3;            // S: q half     == PV: key half kh
  const int kh   = sq;

  __shared__ s16  Pt[2][64][128];     // P^T, rows q (256B), swizzled 16B slots
  __shared__ float Lsum[64][8];
  __shared__ float Ored[8][32][64];   // kh=1 partial O for cross-kh reduction

  // Q B-frags persistent: B[d=8*quad+j][q = sq*32 + 16tq + l15]
  const s16* qbase = Qw + ((size_t)b * NPIX + n0 + sq * 32) * DQK;
  short8 qb[2];
  #pragma unroll
  for (int tq = 0; tq < 2; ++tq)
    qb[tq] = *(const short8*)(qbase + (size_t)(16 * tq + l15) * DQK + quad * 8);

  floatx16 o[2];                      // o[0]: q 0..31, o[1]: q 32..63
  #pragma unroll
  for (int i = 0; i < 16; ++i) { o[0][i] = 0.f; o[1][i] = 0.f; }
  float l_part[2] = {0.f, 0.f};

  const s16* kbase = Kw + (size_t)b * NPIX * DQK;
  const s16* vtb   = Vt + ((size_t)(b * 8 + sw) * 256) * 512 + lane * 8;

  // prefetch tile 0: K strip + V A-frags (coalesced 1KB tiled loads)
  short8 ka_c, ka_n, va[4];
  ka_c = *(const short8*)(kbase + (size_t)(16 * sw + l15) * DQK + quad * 8);
  #pragma unroll
  for (int ks = 0; ks < 4; ++ks)
    va[ks] = *(const short8*)(vtb + (size_t)(ks + 4 * kh) * 512);

  const int wslot = (((2 * sw + (quad >> 1)) ^ l7) << 3) + (quad & 1) * 4;

  // ---- prologue: S for tile 0 -> Pt[0] ----
  {
    floatx4 sacc[2];
    #pragma unroll
    for (int tq = 0; tq < 2; ++tq)
      sacc[tq] = __builtin_amdgcn_mfma_f32_16x16x32_bf16(
                   ka_c, qb[tq], (floatx4){0.f, 0.f, 0.f, 0.f}, 0, 0, 0);
    ka_n = *(const short8*)(kbase + (size_t)(128 + 16 * sw + l15) * DQK + quad * 8);
    #pragma unroll
    for (int tq = 0; tq < 2; ++tq) {
      float p0 = fexp2(fminf(sacc[tq][0], 86.f));
      float p1 = fexp2(fminf(sacc[tq][1], 86.f));
      float p2 = fexp2(fminf(sacc[tq][2], 86.f));
      float p3 = fexp2(fminf(sacc[tq][3], 86.f));
      l_part[tq] += (p0 + p1) + (p2 + p3);
      uint2 pk; pk.x = pk2(p0, p1); pk.y = pk2(p2, p3);
      *(uint2*)&Pt[0][sq * 32 + 16 * tq + l15][wslot] = pk;
    }
    ka_c = ka_n;
  }
  __syncthreads();

  for (int kt = 0; kt < 32; ++kt) {
    const int buf = kt & 1;

    // ---- 1) issue Pt reads for tile kt (latency hides under S below) ----
    short8 pb[4][2];
    #pragma unroll
    for (int ks = 0; ks < 4; ++ks) {
      const int rslot = ((2 * (ks + 4 * kh) + lh) ^ l7) << 3;
      pb[ks][0] = *(const short8*)&Pt[buf][l31     ][rslot];
      pb[ks][1] = *(const short8*)&Pt[buf][32 + l31][rslot];
    }

    // ---- 2) S for tile kt+1 -> Pt[buf^1] (disjoint buffer, no race) ----
    if (kt < 31) {
      floatx4 sacc[2];
      #pragma unroll
      for (int tq = 0; tq < 2; ++tq)
        sacc[tq] = __builtin_amdgcn_mfma_f32_16x16x32_bf16(
                     ka_c, qb[tq], (floatx4){0.f, 0.f, 0.f, 0.f}, 0, 0, 0);
      const int mn2 = (kt < 30) ? (kt + 2) * 128 : 0;
      ka_n = *(const short8*)(kbase + (size_t)(mn2 + 16 * sw + l15) * DQK + quad * 8);
      #pragma unroll
      for (int tq = 0; tq < 2; ++tq) {
        float p0 = fexp2(fminf(sacc[tq][0], 86.f));
        float p1 = fexp2(fminf(sacc[tq][1], 86.f));
        float p2 = fexp2(fminf(sacc[tq][2], 86.f));
        float p3 = fexp2(fminf(sacc[tq][3], 86.f));
        l_part[tq] += (p0 + p1) + (p2 + p3);
        uint2 pk; pk.x = pk2(p0, p1); pk.y = pk2(p2, p3);
        *(uint2*)&Pt[buf ^ 1][sq * 32 + 16 * tq + l15][wslot] = pk;
      }
      ka_c = ka_n;
    }

    // ---- 3) PV: O[32ch][64q] += V[32ch][64k_half]·P^T[64k_half][64q] ----
    __builtin_amdgcn_s_setprio(1);
    #pragma unroll
    for (int ks = 0; ks < 4; ++ks) {
      o[0] = __builtin_amdgcn_mfma_f32_32x32x16_bf16(va[ks], pb[ks][0], o[0], 0, 0, 0);
      o[1] = __builtin_amdgcn_mfma_f32_32x32x16_bf16(va[ks], pb[ks][1], o[1], 0, 0, 0);
    }
    __builtin_amdgcn_s_setprio(0);

    // ---- 4) V refill for tile kt+1 (wraps harmlessly at kt=31) ----
    const int sn = ((kt + 1) & 31) * 8;
    #pragma unroll
    for (int ks = 0; ks < 4; ++ks)
      va[ks] = *(const short8*)(vtb + (size_t)(sn + ks + 4 * kh) * 512);

    __syncthreads();   // publish Pt[buf^1]; all reads of Pt[buf] done
  }

  // ---- final l reduction: quads (shfl) then strips (LDS, once) ----
  #pragma unroll
  for (int tq = 0; tq < 2; ++tq) {
    l_part[tq] += __shfl_xor(l_part[tq], 16);
    l_part[tq] += __shfl_xor(l_part[tq], 32);
  }
  if (quad == 0) {
    #pragma unroll
    for (int tq = 0; tq < 2; ++tq) Lsum[sq * 32 + 16 * tq + l15][sw] = l_part[tq];
  }
  // kh=1 waves stage their partial O for reduction
  if (kh == 1) {
    #pragma unroll
    for (int r = 0; r < 16; ++r) {
      const int chrow = (r & 3) + 8 * (r >> 2) + 4 * lh;
      Ored[sw][chrow][l31]      = o[0][r];
      Ored[sw][chrow][32 + l31] = o[1][r];
    }
  }
  __syncthreads();

  // ---- epilogue (kh=0 waves): sum key-halves, normalize, residual ----
  if (kh == 0) {
    const int q0 = l31, q1 = 32 + l31;
    float4 a0 = *(const float4*)&Lsum[q0][0];
    float4 a1 = *(const float4*)&Lsum[q0][4];
    float4 b0 = *(const float4*)&Lsum[q1][0];
    float4 b1 = *(const float4*)&Lsum[q1][4];
    float inv0 = 1.f / (((a0.x + a0.y) + (a0.z + a0.w)) +
                        ((a1.x + a1.y) + (a1.z + a1.w)));
    float inv1 = 1.f / (((b0.x + b0.y) + (b0.z + b0.w)) +
                        ((b1.x + b1.y) + (b1.z + b1.w)));
    #pragma unroll
    for (int r = 0; r < 16; ++r) {
      const int chrow = (r & 3) + 8 * (r >> 2) + 4 * lh;
      const int ch = sw * 32 + chrow;
      const float s0 = o[0][r] + Ored[sw][chrow][l31];
      const float s1 = o[1][r] + Ored[sw][chrow][32 + l31];
      const size_t off0 = ((size_t)b * CH + ch) * NPIX + n0 + q0;
      const size_t off1 = ((size_t)b * CH + ch) * NPIX + n0 + q1;
      out[off0] = fmaf(s0, inv0, x[off0]);
      out[off1] = fmaf(s1, inv1, x[off1]);
    }
  }
}

extern "C" void kernel_launch(void* const* d_in, const int* in_sizes, int n_in,
                              void* d_out, int out_size, void* d_ws, size_t ws_size,
                              hipStream_t stream) {
  (void)in_sizes; (void)n_in; (void)out_size; (void)ws_size;
  const float* x  = (const float*)d_in[0];
  const float* Wq = (const float*)d_in[1];
  const float* bq = (const float*)d_in[2];
  const float* Wk = (const float*)d_in[3];
  const float* bk = (const float*)d_in[4];
  const float* Wv = (const float*)d_in[5];
  const float* bv = (const float*)d_in[6];
  float* out = (float*)d_out;

  // ws: Qw 1 MiB @0 | Kw @1 MiB | Vt @2 MiB (8 MiB, tiled) | Wbf @10 MiB |
  //     Bsw @10.25 MiB
  unsigned char* ws = (unsigned char*)d_ws;
  s16*   Qw  = (s16*)ws;
  s16*   Kw  = (s16*)(ws + (size_t)1 * 1024 * 1024);
  s16*   Vt  = (s16*)(ws + (size_t)2 * 1024 * 1024);
  s16*   Wbf = (s16*)(ws + (size_t)10 * 1024 * 1024);
  float* Bsw = (float*)(ws + (size_t)10 * 1024 * 1024 + 256 * 1024);

  hipLaunchKernelGGL(prepack, dim3(80), dim3(256), 0, stream,
                     Wq, bq, Wk, bk, Wv, bv, Wbf, Bsw);
  hipLaunchKernelGGL(proj_mfma, dim3(512), dim3(256), 0, stream,
                     x, Wbf, Bsw, Qw, Kw, Vt);
  hipLaunchKernelGGL(attn_mfma, dim3(256), dim3(1024), 0, stream,
                     Qw, Kw, Vt, x, out);
}